// Round 1
// baseline (496.616 us; speedup 1.0000x reference)
//
#include <hip/hip_runtime.h>
#include <cstdint>

typedef unsigned short u16;
typedef __bf16 bf16x8 __attribute__((ext_vector_type(8)));
typedef float f32x4 __attribute__((ext_vector_type(4)));

constexpr int Bc = 2, Sc = 2048, Dc = 1024, Hc = 16, DHc = 64;

__device__ __forceinline__ u16 f2bf(float f) {
  uint32_t u = __builtin_bit_cast(uint32_t, f);
  u += 0x7fffu + ((u >> 16) & 1u);
  return (u16)(u >> 16);
}
__device__ __forceinline__ float bf2f(u16 h) {
  uint32_t u = ((uint32_t)h) << 16;
  return __builtin_bit_cast(float, u);
}
__device__ __forceinline__ f32x4 mfma16(bf16x8 a, bf16x8 b, f32x4 c) {
  return __builtin_amdgcn_mfma_f32_16x16x32_bf16(a, b, c, 0, 0, 0);
}

// ---------------- f32 -> bf16 conversion, 4 elems/thread ----------------
__global__ __launch_bounds__(256) void cvt_kernel(const float* __restrict__ in,
                                                  u16* __restrict__ out, int n4) {
  int i = blockIdx.x * 256 + threadIdx.x;
  if (i >= n4) return;
  float4 v = reinterpret_cast<const float4*>(in)[i];
  ushort4 o;
  o.x = f2bf(v.x); o.y = f2bf(v.y); o.z = f2bf(v.z); o.w = f2bf(v.w);
  reinterpret_cast<ushort4*>(out)[i] = o;
}

// ---------------- generic bf16 GEMM: C[m][n] = (sum_k A[m][k]*B[n][k] + bias[n]) * scale
// Output mapping: m = b*2048 + s; n = hh*DHn + ee;
//   idx = b*strideB + s*strideS + hh*strideH + ee*strideE  (writes bf16 or f32)
__global__ __launch_bounds__(256) void gemm_bt(
    const u16* __restrict__ A, const u16* __restrict__ Bw,
    const float* __restrict__ bias, int M, int N, int K, float scale,
    u16* __restrict__ outb, float* __restrict__ outf,
    int DHn, long strideB, long strideS, long strideH, long strideE) {
  constexpr int LDK = 40;  // 32 + 8 pad -> conflict-free ds_read_b128
  __shared__ u16 As[128 * LDK];
  __shared__ u16 Bs[128 * LDK];
  const int tid = threadIdx.x;
  const int lane = tid & 63;
  const int w = tid >> 6, wm = w >> 1, wn = w & 1;
  const int lo = lane & 15, hi = lane >> 4;
  const int m0 = blockIdx.y * 128, n0 = blockIdx.x * 128;
  const f32x4 vzero = {0.f, 0.f, 0.f, 0.f};

  f32x4 acc[4][4];
  #pragma unroll
  for (int i = 0; i < 4; ++i)
    #pragma unroll
    for (int j = 0; j < 4; ++j) acc[i][j] = vzero;

  for (int k0 = 0; k0 < K; k0 += 32) {
    #pragma unroll
    for (int it = 0; it < 2; ++it) {
      const int e = (tid + it * 256) * 8;
      const int r = e >> 5, c = e & 31;
      *reinterpret_cast<uint4*>(&As[r * LDK + c]) =
          *reinterpret_cast<const uint4*>(&A[(long)(m0 + r) * K + k0 + c]);
      int nr = n0 + r; nr = nr < N ? nr : N - 1;  // clamp (vproj N=64)
      *reinterpret_cast<uint4*>(&Bs[r * LDK + c]) =
          *reinterpret_cast<const uint4*>(&Bw[(long)nr * K + k0 + c]);
    }
    __syncthreads();
    bf16x8 af[4], bfr[4];
    #pragma unroll
    for (int mi = 0; mi < 4; ++mi)
      af[mi] = *reinterpret_cast<const bf16x8*>(&As[(wm * 64 + mi * 16 + lo) * LDK + hi * 8]);
    #pragma unroll
    for (int nj = 0; nj < 4; ++nj)
      bfr[nj] = *reinterpret_cast<const bf16x8*>(&Bs[(wn * 64 + nj * 16 + lo) * LDK + hi * 8]);
    #pragma unroll
    for (int mi = 0; mi < 4; ++mi)
      #pragma unroll
      for (int nj = 0; nj < 4; ++nj)
        acc[mi][nj] = mfma16(af[mi], bfr[nj], acc[mi][nj]);
    __syncthreads();
  }

  #pragma unroll
  for (int nj = 0; nj < 4; ++nj) {
    const int n = n0 + wn * 64 + nj * 16 + lo;
    if (n >= N) continue;
    const float bb = bias ? bias[n] : 0.f;
    const int hh = n / DHn, ee = n % DHn;
    #pragma unroll
    for (int mi = 0; mi < 4; ++mi) {
      #pragma unroll
      for (int r = 0; r < 4; ++r) {
        const int mm = m0 + wm * 64 + mi * 16 + hi * 4 + r;
        const int bidx = mm >> 11, ss = mm & 2047;  // S = 2048
        const long idx = bidx * strideB + ss * strideS + hh * strideH + ee * strideE;
        const float val = (acc[mi][nj][r] + bb) * scale;
        if (outf) outf[idx] = val;
        else outb[idx] = f2bf(val);
      }
    }
  }
}

// ---------------- fused causal attention (2-loop flash, writes full attn matrix)
// qh,kh: [B,H,S,DH] bf16 (qh pre-scaled by 1/8). vT: [B,DH,S] bf16.
// outh: [B,H,S,DH] bf16. attn_out: [B,S,H,S] f32.
__global__ __launch_bounds__(256) void attn_kernel(
    const u16* __restrict__ qh, const u16* __restrict__ kh,
    const u16* __restrict__ vT, u16* __restrict__ outh,
    float* __restrict__ attn_out) {
  __shared__ u16 plds[4 * 16 * 40];  // per-wave P-transpose buffer, padded
  const int tid = threadIdx.x;
  const int lane = tid & 63, w = tid >> 6;
  const int lo = lane & 15, hi = lane >> 4;
  const int blk = blockIdx.x;
  const int sb = blk & 31, h = (blk >> 5) & 15, b = blk >> 9;
  const int s0 = sb * 64 + w * 16;
  const int smax = s0 + 15;
  const long bh = (long)(b * Hc + h) * Sc;
  const f32x4 vzero = {0.f, 0.f, 0.f, 0.f};

  // Q fragments (K = 64 -> two k-steps of 32)
  bf16x8 qa0, qa1;
  {
    const u16* qp = &qh[(bh + s0 + lo) * DHc];
    qa0 = *reinterpret_cast<const bf16x8*>(&qp[hi * 8]);
    qa1 = *reinterpret_cast<const bf16x8*>(&qp[32 + hi * 8]);
  }

  // ---- loop 1: online max/sum over causal range ----
  float mr[4], lr[4];
  #pragma unroll
  for (int r = 0; r < 4; ++r) { mr[r] = -1e30f; lr[r] = 0.f; }

  for (int t0 = 0; t0 <= smax; t0 += 16) {
    const u16* kp = &kh[(bh + t0 + lo) * DHc];
    bf16x8 kb0 = *reinterpret_cast<const bf16x8*>(&kp[hi * 8]);
    bf16x8 kb1 = *reinterpret_cast<const bf16x8*>(&kp[32 + hi * 8]);
    f32x4 z = vzero;
    z = mfma16(qa0, kb0, z);
    z = mfma16(qa1, kb1, z);
    const int t = t0 + lo;
    #pragma unroll
    for (int r = 0; r < 4; ++r) {
      const int s = s0 + hi * 4 + r;
      const bool ok = (t <= s);
      const float zv = ok ? z[r] : -1e30f;
      const float mn = fmaxf(mr[r], zv);
      const float p = ok ? __expf(z[r] - mn) : 0.f;
      lr[r] = lr[r] * __expf(mr[r] - mn) + p;
      mr[r] = mn;
    }
  }
  // reduce (m,l) across the 16 column-lanes (butterfly stays in 16-lane group)
  #pragma unroll
  for (int r = 0; r < 4; ++r) {
    #pragma unroll
    for (int dd = 1; dd < 16; dd <<= 1) {
      const float mo = __shfl_xor(mr[r], dd);
      const float lx = __shfl_xor(lr[r], dd);
      const float mn = fmaxf(mr[r], mo);
      lr[r] = lr[r] * __expf(mr[r] - mn) + lx * __expf(mo - mn);
      mr[r] = mn;
    }
    lr[r] = 1.f / lr[r];  // inverse denom
  }

  // ---- loop 2: recompute, write normalized P, accumulate PV ----
  f32x4 acco[4];
  #pragma unroll
  for (int eb = 0; eb < 4; ++eb) acco[eb] = vzero;
  u16* pbuf = &plds[w * 16 * 40];

  for (int tc = 0; tc < Sc; tc += 32) {
    float pv[2][4];
    const bool live = (tc <= smax);  // wave-uniform
    if (live) {
      #pragma unroll
      for (int ti = 0; ti < 2; ++ti) {
        const int t0 = tc + ti * 16;
        const u16* kp = &kh[(bh + t0 + lo) * DHc];
        bf16x8 kb0 = *reinterpret_cast<const bf16x8*>(&kp[hi * 8]);
        bf16x8 kb1 = *reinterpret_cast<const bf16x8*>(&kp[32 + hi * 8]);
        f32x4 z = vzero;
        z = mfma16(qa0, kb0, z);
        z = mfma16(qa1, kb1, z);
        const int t = t0 + lo;
        #pragma unroll
        for (int r = 0; r < 4; ++r) {
          const int s = s0 + hi * 4 + r;
          pv[ti][r] = (t <= s) ? __expf(z[r] - mr[r]) * lr[r] : 0.f;
        }
      }
    } else {
      #pragma unroll
      for (int ti = 0; ti < 2; ++ti)
        #pragma unroll
        for (int r = 0; r < 4; ++r) pv[ti][r] = 0.f;
    }
    // write attn probabilities (including zeros above diagonal)
    #pragma unroll
    for (int ti = 0; ti < 2; ++ti) {
      const int t = tc + ti * 16 + lo;
      #pragma unroll
      for (int r = 0; r < 4; ++r) {
        const int s = s0 + hi * 4 + r;
        attn_out[((long)(b * Sc + s) * Hc + h) * Sc + t] = pv[ti][r];
      }
    }
    if (live) {
      // transpose P tile via per-wave LDS into A-fragment layout
      #pragma unroll
      for (int ti = 0; ti < 2; ++ti)
        #pragma unroll
        for (int r = 0; r < 4; ++r)
          pbuf[(hi * 4 + r) * 40 + ti * 16 + lo] = f2bf(pv[ti][r]);
      asm volatile("s_waitcnt lgkmcnt(0)" ::: "memory");
      __builtin_amdgcn_sched_barrier(0);
      bf16x8 pa = *reinterpret_cast<const bf16x8*>(&pbuf[lo * 40 + hi * 8]);
      #pragma unroll
      for (int eb = 0; eb < 4; ++eb) {
        bf16x8 vb = *reinterpret_cast<const bf16x8*>(
            &vT[((long)b * DHc + eb * 16 + lo) * Sc + tc + hi * 8]);
        acco[eb] = mfma16(pa, vb, acco[eb]);
      }
    }
  }
  #pragma unroll
  for (int eb = 0; eb < 4; ++eb)
    #pragma unroll
    for (int r = 0; r < 4; ++r) {
      const int s = s0 + hi * 4 + r;
      outh[(bh + s) * DHc + eb * 16 + lo] = f2bf(acco[eb][r]);
    }
}

// ---------------- mean over heads: outh [B,H,S,DH] bf16 -> mean [B*S,DH] bf16 (x 1/16)
__global__ __launch_bounds__(256) void mean_kernel(const u16* __restrict__ outh,
                                                   u16* __restrict__ meanb) {
  const int idx = blockIdx.x * 256 + threadIdx.x;  // 32768 threads
  const int bs = idx >> 3;
  const int e0 = (idx & 7) * 8;
  const int b = bs >> 11, s = bs & 2047;
  float acc[8];
  #pragma unroll
  for (int j = 0; j < 8; ++j) acc[j] = 0.f;
  for (int h = 0; h < Hc; ++h) {
    alignas(16) u16 tmp[8];
    *reinterpret_cast<uint4*>(tmp) =
        *reinterpret_cast<const uint4*>(&outh[((long)(b * Hc + h) * Sc + s) * DHc + e0]);
    #pragma unroll
    for (int j = 0; j < 8; ++j) acc[j] += bf2f(tmp[j]);
  }
  alignas(16) u16 o[8];
  #pragma unroll
  for (int j = 0; j < 8; ++j) o[j] = f2bf(acc[j] * 0.0625f);
  *reinterpret_cast<uint4*>(&meanb[(long)bs * DHc + e0]) = *reinterpret_cast<const uint4*>(o);
}

extern "C" void kernel_launch(void* const* d_in, const int* in_sizes, int n_in,
                              void* d_out, int out_size, void* d_ws, size_t ws_size,
                              hipStream_t stream) {
  (void)in_sizes; (void)n_in; (void)out_size; (void)ws_size;
  const float* q  = (const float*)d_in[0];
  const float* k  = (const float*)d_in[1];
  const float* v  = (const float*)d_in[2];
  const float* Wv = (const float*)d_in[4];
  const float* bv = (const float*)d_in[5];
  const float* Wq = (const float*)d_in[6];
  const float* bq = (const float*)d_in[7];
  const float* Wk = (const float*)d_in[8];
  const float* bk = (const float*)d_in[9];
  const float* Wo = (const float*)d_in[10];

  char* ws = (char*)d_ws;
  u16* qbf   = (u16*)(ws + 0);          // 8.0 MB
  u16* kbf   = (u16*)(ws + 8388608);
  u16* vbf   = (u16*)(ws + 16777216);
  u16* Wqbf  = (u16*)(ws + 25165824);   // 2 MB
  u16* Wkbf  = (u16*)(ws + 27262976);
  u16* Wvbf  = (u16*)(ws + 29360128);   // 128 KB
  u16* Wobf  = (u16*)(ws + 29491200);
  u16* qhb   = (u16*)(ws + 29622272);   // 8 MB  [B,H,S,DH]
  u16* khb   = (u16*)(ws + 38010880);
  u16* vTb   = (u16*)(ws + 46399488);   // 512 KB [B,DH,S]
  u16* outh  = (u16*)(ws + 46923776);   // 8 MB  [B,H,S,DH]
  u16* meanb = (u16*)(ws + 55312384);   // 512 KB

  float* outp  = (float*)d_out;
  float* attnp = (float*)d_out + (long)Bc * Sc * Dc;  // 4194304

  auto cvt = [&](const float* in, u16* out, int n) {
    cvt_kernel<<<(n / 4 + 255) / 256, 256, 0, stream>>>(in, out, n / 4);
  };
  cvt(q,  qbf,  Bc * Sc * Dc);
  cvt(k,  kbf,  Bc * Sc * Dc);
  cvt(v,  vbf,  Bc * Sc * Dc);
  cvt(Wq, Wqbf, Hc * DHc * Dc);
  cvt(Wk, Wkbf, Hc * DHc * Dc);
  cvt(Wv, Wvbf, DHc * Dc);
  cvt(Wo, Wobf, Dc * DHc);

  const int M = Bc * Sc;  // 4096
  // qh = (q @ Wq^T + bq) / 8   -> [B,H,S,DH] bf16
  gemm_bt<<<dim3(8, 32), 256, 0, stream>>>(qbf, Wqbf, bq, M, 1024, 1024, 0.125f,
      qhb, nullptr, 64, 2097152L, 64L, 131072L, 1L);
  // kh = k @ Wk^T + bk         -> [B,H,S,DH] bf16
  gemm_bt<<<dim3(8, 32), 256, 0, stream>>>(kbf, Wkbf, bk, M, 1024, 1024, 1.0f,
      khb, nullptr, 64, 2097152L, 64L, 131072L, 1L);
  // vT = (v @ Wv^T + bv)^T     -> [B,DH,S] bf16
  gemm_bt<<<dim3(1, 32), 256, 0, stream>>>(vbf, Wvbf, bv, M, 64, 1024, 1.0f,
      vTb, nullptr, 64, 131072L, 1L, 0L, 2048L);

  attn_kernel<<<Bc * Hc * (Sc / 64), 256, 0, stream>>>(qhb, khb, vTb, outh, attnp);

  mean_kernel<<<128, 256, 0, stream>>>(outh, meanb);

  // out = mean @ Wo^T          -> [B,S,D] f32
  gemm_bt<<<dim3(8, 32), 256, 0, stream>>>(meanb, Wobf, nullptr, M, 1024, 64, 1.0f,
      nullptr, outp, 1024, 2097152L, 1024L, 0L, 1L);
}